// Round 11
// baseline (237.347 us; speedup 1.0000x reference)
//
#include <hip/hip_runtime.h>
#include <hip/hip_bf16.h>

#define SEQ 2048
#define DM  1024
#define NH  16
#define HDM 64

typedef __hip_bfloat16 bf16;
typedef __bf16 bhalf8 __attribute__((ext_vector_type(8)));
typedef float floatx4 __attribute__((ext_vector_type(4)));

__device__ __forceinline__ void async_cp16(const void* g, void* l) {
  __builtin_amdgcn_global_load_lds(
      (const __attribute__((address_space(1))) void*)g,
      (__attribute__((address_space(3))) void*)l, 16, 0, 0);
}

// ---- fused prep: x f32->bf16; rel f32->bf16 padded [4096][64]; W transpose
__global__ __launch_bounds__(256) void prep(
    const float* __restrict__ x, const float* __restrict__ T,
    const float* __restrict__ W0, const float* __restrict__ W1,
    const float* __restrict__ W2, const float* __restrict__ W3,
    bf16* __restrict__ xbf, bf16* __restrict__ Tbf, bf16* __restrict__ WtBase)
{
  __shared__ float tile[64][69];
  const int b = blockIdx.x;
  const int tid = threadIdx.x;
  if (b < 2048) {
    int c = b * 256 + tid;
    float4 v = *(const float4*)&x[(size_t)c * 4];
    union { bf16 h[4]; float2 f; } u;
    u.h[0] = __float2bfloat16(v.x); u.h[1] = __float2bfloat16(v.y);
    u.h[2] = __float2bfloat16(v.z); u.h[3] = __float2bfloat16(v.w);
    *(float2*)&xbf[(size_t)c * 4] = u.f;
  } else if (b < 2304) {
    int ct = (b - 2048) * 256 + tid;       // [0, 65536)
    union { bf16 h[4]; float2 f; } u;
#pragma unroll
    for (int e = 0; e < 4; ++e) {
      int se = ct * 4 + e;
      if (se >= 4095 * 64) se -= 64;       // pad row 4095 = dup of 4094
      u.h[e] = __float2bfloat16(T[se]);
    }
    *(float2*)&Tbf[(size_t)ct * 4] = u.f;
  } else {
    int tb = b - 2304;                     // [0, 1024)
    int z = tb >> 8, rem = tb & 255;
    const float* W = (z == 0) ? W0 : (z == 1) ? W1 : (z == 2) ? W2 : W3;
    bf16* Wt = WtBase + (size_t)z * DM * DM;
    const int kb = (rem >> 4) * 64, nb = (rem & 15) * 64;
    const int r = tid >> 4, c4 = (tid & 15) * 4;
#pragma unroll
    for (int rr = 0; rr < 4; ++rr) {
      float4 v = *(const float4*)&W[(size_t)(kb + rr * 16 + r) * DM + nb + c4];
      tile[rr * 16 + r][c4 + 0] = v.x; tile[rr * 16 + r][c4 + 1] = v.y;
      tile[rr * 16 + r][c4 + 2] = v.z; tile[rr * 16 + r][c4 + 3] = v.w;
    }
    __syncthreads();
    const int w = tid >> 6, l = tid & 63;
#pragma unroll
    for (int i = 0; i < 16; ++i) {
      int n = nb + w * 16 + i;
      Wt[(size_t)n * DM + kb + l] = __float2bfloat16(tile[l][w * 16 + i]);
    }
  }
}

// ---- MFMA GEMM core 64x64 (gemm_out): BK=64 as two BK=32 panels.
// Chunk XOR swizzle: linear DMA dest + inverse-swizzled global source +
// swizzled read. Validated rounds 3-9.
__device__ __forceinline__ void gemm64_core(
    const bf16* __restrict__ A, const bf16* __restrict__ Bt,
    bf16* As, bf16* Bs, int bm, int bn, floatx4 (&acc)[4])
{
  const int tid = threadIdx.x;
  const int lane = tid & 63;
  const int w = tid >> 6;
  const int ln15 = lane & 15, quad = lane >> 4;
  const int qs8  = (quad ^ ((ln15 >> 1) & 3)) * 8;        // swizzled read col
  const int srow = tid >> 2;                               // staging phys row
  const int scol = ((tid & 3) ^ ((tid >> 3) & 3)) * 8;     // swizzled src col

  for (int k0 = 0; k0 < DM; k0 += 64) {
    async_cp16(A  + (size_t)(bm + srow) * DM + k0 + scol,      As + tid * 8);
    async_cp16(A  + (size_t)(bm + srow) * DM + k0 + 32 + scol, As + 2048 + tid * 8);
    async_cp16(Bt + (size_t)(bn + srow) * DM + k0 + scol,      Bs + tid * 8);
    async_cp16(Bt + (size_t)(bn + srow) * DM + k0 + 32 + scol, Bs + 2048 + tid * 8);
    __syncthreads();
#pragma unroll
    for (int kk = 0; kk < 2; ++kk) {
      bhalf8 af = *(bhalf8*)&As[kk * 2048 + (w * 16 + ln15) * 32 + qs8];
      bhalf8 bfr[4];
#pragma unroll
      for (int j = 0; j < 4; ++j)
        bfr[j] = *(bhalf8*)&Bs[kk * 2048 + (j * 16 + ln15) * 32 + qs8];
#pragma unroll
      for (int j = 0; j < 4; ++j)
        acc[j] = __builtin_amdgcn_mfma_f32_16x16x32_bf16(af, bfr[j], acc[j], 0, 0, 0);
    }
    __syncthreads();
  }
}

// ---- QKV projection, 128x128 tile, BK=64, 4 waves in 2x2, chunk-XOR swizzle.
// z==1 (K) output scaled by 1/8 (bf16-exact).
__global__ __launch_bounds__(256) void gemm_qkv128(
    const bf16* __restrict__ A, const bf16* __restrict__ Wt3,
    const float* __restrict__ bq, const float* __restrict__ bk,
    const float* __restrict__ bv, bf16* __restrict__ outbase)
{
  __shared__ __align__(16) bf16 As[128 * 64];
  __shared__ __align__(16) bf16 Bs[128 * 64];
  const int z = blockIdx.z;
  const bf16* Bt = Wt3 + (size_t)z * DM * DM;
  const float* bias = (z == 0) ? bq : (z == 1) ? bk : bv;
  const float kscale = (z == 1) ? 0.125f : 1.0f;
  bf16* C = outbase + (size_t)z * SEQ * DM;
  const int bm = blockIdx.y * 128, bn = blockIdx.x * 128;
  const int tid = threadIdx.x;
  const int lane = tid & 63, w = tid >> 6;
  const int ln15 = lane & 15, quad = lane >> 4;
  const int wr = (w >> 1) * 64, wc = (w & 1) * 64;

  floatx4 acc[4][4];
#pragma unroll
  for (int mi = 0; mi < 4; ++mi)
#pragma unroll
    for (int nj = 0; nj < 4; ++nj) acc[mi][nj] = (floatx4){0.f, 0.f, 0.f, 0.f};

  for (int k0 = 0; k0 < DM; k0 += 64) {
#pragma unroll
    for (int t = 0; t < 4; ++t) {
      int cid = t * 256 + tid;
      int row = cid >> 3;
      int scol = ((cid & 7) ^ (row & 7)) * 8;   // inverse-swizzled source col
      async_cp16(A  + (size_t)(bm + row) * DM + k0 + scol, As + cid * 8);
      async_cp16(Bt + (size_t)(bn + row) * DM + k0 + scol, Bs + cid * 8);
    }
    __syncthreads();
#pragma unroll
    for (int kk = 0; kk < 2; ++kk) {
      const int chs = ((kk * 4 + quad) ^ (ln15 & 7)) * 8;  // swizzled read col
      bhalf8 af[4], bfr[4];
#pragma unroll
      for (int mi = 0; mi < 4; ++mi)
        af[mi] = *(bhalf8*)&As[(wr + mi * 16 + ln15) * 64 + chs];
#pragma unroll
      for (int nj = 0; nj < 4; ++nj)
        bfr[nj] = *(bhalf8*)&Bs[(wc + nj * 16 + ln15) * 64 + chs];
#pragma unroll
      for (int mi = 0; mi < 4; ++mi)
#pragma unroll
        for (int nj = 0; nj < 4; ++nj)
          acc[mi][nj] = __builtin_amdgcn_mfma_f32_16x16x32_bf16(
              af[mi], bfr[nj], acc[mi][nj], 0, 0, 0);
    }
    __syncthreads();
  }

#pragma unroll
  for (int nj = 0; nj < 4; ++nj) {
    int col = bn + wc + nj * 16 + ln15;
    float bv_ = bias[col];
#pragma unroll
    for (int mi = 0; mi < 4; ++mi) {
#pragma unroll
      for (int r = 0; r < 4; ++r) {
        int row = bm + wr + mi * 16 + quad * 4 + r;
        float v = (acc[mi][nj][r] + bv_) * kscale;
        if (z < 2)
          C[((size_t)(col >> 6) * SEQ + row) * HDM + (col & 63)] = __float2bfloat16(v);
        else
          C[(size_t)col * SEQ + row] = __float2bfloat16(v);
      }
    }
  }
}

// ---- output projection: f32 out row-major
__global__ __launch_bounds__(256) void gemm_out(
    const bf16* __restrict__ A, const bf16* __restrict__ Bt,
    const float* __restrict__ bias, float* __restrict__ C)
{
  __shared__ __align__(16) bf16 As[64 * 64];
  __shared__ __align__(16) bf16 Bs[64 * 64];
  const int bm = blockIdx.y * 64, bn = blockIdx.x * 64;
  floatx4 acc[4];
#pragma unroll
  for (int j = 0; j < 4; ++j) acc[j] = (floatx4){0.f, 0.f, 0.f, 0.f};
  gemm64_core(A, Bt, As, Bs, bm, bn, acc);

  const int lane = threadIdx.x & 63;
  const int w = threadIdx.x >> 6;
  const int ln15 = lane & 15, quad = lane >> 4;
#pragma unroll
  for (int j = 0; j < 4; ++j) {
    int col = bn + j * 16 + ln15;
    float bv_ = bias[col];
#pragma unroll
    for (int r = 0; r < 4; ++r) {
      int row = bm + w * 16 + quad * 4 + r;
      C[(size_t)row * DM + col] = acc[j][r] + bv_;
    }
  }
}

// ---- Flash attention. Round-10 restructure for 3 blocks/CU (was 2):
// LDS 75264 -> 50176 B via (a) T tiles no longer LDS-staged -- fresh-band
// B-frags read DIRECT from global (T tile at (i0,jt) is shared by all 32
// (h,z)-blocks -> L1/L2-hot; carry-init has used this path since r7);
// (b) Q loaded straight to registers (per-lane contiguous 16 B); (c) S2c
// and Ps UNIONED in per-wave-private slabs (16 rows x 272 B stride) --
// S2c reads hoisted to 16 regs before any Ps write, so lifetimes are
// disjoint within a wave; slabs are wave-private so no cross-wave alias;
// loop-top barrier orders PV-reads vs next-iter scatter. K/V keep the
// r9-validated staged+double-buffered+chunk-XOR path (r3 lesson: staging
// IS the latency-hiding; only the L1-hot T leaves LDS).
__global__ __launch_bounds__(256, 3) void attn_flash(
    const bf16* __restrict__ Q, const bf16* __restrict__ K,
    const bf16* __restrict__ Vt, const bf16* __restrict__ Tb,
    bf16* __restrict__ Opart, float* __restrict__ lws)
{
  const int i0   = blockIdx.x * 64;
  const int h    = blockIdx.y;
  const int z    = blockIdx.z;
  const int tid  = threadIdx.x;
  const int lane = tid & 63;
  const int w    = tid >> 6;
  const int wrow = w * 16;
  const int ln15 = lane & 15;
  const int quad = lane >> 4;

  // [0,16384) K dbuf | [16384,32768) V dbuf | [32768,50176) 4 wave slabs
  // slab(w): 16 rows x 272 B. S2c f32 [16][68] / Ps bf16 rows (128 B used).
  __shared__ __align__(16) unsigned char smem[50176];
  unsigned char* slab = smem + 32768 + w * 4352;
  float* S2w = (float*)slab;            // stride 68 f32 per row
  bf16*  Psw = (bf16*)slab;             // stride 136 bf16 per row

  const bf16* Qg = Q  + ((size_t)h * SEQ + i0) * HDM;
  const bf16* Kg = K  + (size_t)h * SEQ * HDM;
  const bf16* Vg = Vt + (size_t)h * HDM * SEQ;

  // staging (K/V only): dest linear, global source chunk pre-swizzled so
  // phys[row][c] = logical[row][c ^ ((row>>1)&3)]
  const int r4 = tid >> 2;
  const int c8s = (((tid & 3) ^ ((r4 >> 1) & 3)) * 8);
  auto stage = [&](int jt_, int b) {
    int j0_ = jt_ * 64;
    bf16* Kd = (bf16*)smem + b * 4096;
    bf16* Vd = (bf16*)smem + 8192 + b * 4096;
    async_cp16(Kg + (size_t)(j0_ + r4) * HDM + c8s,        Kd + tid * 8);
    async_cp16(Kg + (size_t)(j0_ + r4) * HDM + 32 + c8s,   Kd + 2048 + tid * 8);
    async_cp16(Vg + (size_t)r4 * SEQ + j0_ + c8s,          Vd + tid * 8);
    async_cp16(Vg + (size_t)r4 * SEQ + j0_ + 32 + c8s,     Vd + 2048 + tid * 8);
  };

  const int jt0 = z * 16;
  stage(jt0, 0);   // prefetch first K/V tile; lands during carry preamble

  // Q fragments straight from global (16 B per lane, one-time)
  const bhalf8 aq0 = *(const bhalf8*)&Qg[(size_t)(wrow + ln15) * HDM + quad * 8];
  const bhalf8 aq1 = *(const bhalf8*)&Qg[(size_t)(wrow + ln15) * HDM + quad * 8 + 32];

  floatx4 o[4];
  float lsum[4];
#pragma unroll
  for (int c = 0; c < 4; ++c) { o[c] = (floatx4){0.f, 0.f, 0.f, 0.f}; lsum[c] = 0.f; }

  const int rb0 = i0 - jt0 * 64 + SEQ - HDM;
  // carry init: virtual previous iter's fresh band (rows rb0+64+[0,64)),
  // direct-global B-frags (rows <= 4095, in padded Tb).
  floatx4 carry[4];
#pragma unroll
  for (int ct = 0; ct < 4; ++ct) {
    const bf16* tr = Tb + (size_t)(rb0 + 64 + ct * 16 + ln15) * HDM + quad * 8;
    bhalf8 b0 = *(const bhalf8*)tr;
    bhalf8 b1 = *(const bhalf8*)(tr + 32);
    floatx4 a = (floatx4){0.f, 0.f, 0.f, 0.f};
    a = __builtin_amdgcn_mfma_f32_16x16x32_bf16(aq0, b0, a, 0, 0, 0);
    a = __builtin_amdgcn_mfma_f32_16x16x32_bf16(aq1, b1, a, 0, 0, 0);
    carry[ct] = a;
  }

  // swizzled frag-read column for K/V tiles (phys = quad ^ ((row>>1)&3))
  const int qsw = (quad ^ ((ln15 >> 1) & 3)) * 8;
  // Ps read columns (local row = ln15): phys chunk = quad ^ (ln15>>1)
  const int pc0 = (quad ^ (ln15 >> 1)) * 8;
  const int pc1 = pc0 ^ 32;

  int cur = 0;
  for (int jt = jt0; jt < jt0 + 16; ++jt) {
    const int j0 = jt * 64;
    const int rb = i0 - j0 + SEQ - HDM;
    __syncthreads();   // drains vmcnt: buf[cur] DMA complete; prev readers done
    if (jt + 1 < jt0 + 16) stage(jt + 1, cur ^ 1);   // overlap with compute
    const bf16* Ksc = (bf16*)smem + cur * 4096;
    const bf16* Vsc = (bf16*)smem + 8192 + cur * 4096;

    // fresh band: rows rb+[0,64) of Tb, B-frags DIRECT from global (L1-hot)
    floatx4 fresh[4];
#pragma unroll
    for (int ct = 0; ct < 4; ++ct) {
      const bf16* tr = Tb + (size_t)(rb + ct * 16 + ln15) * HDM + quad * 8;
      bhalf8 b0 = *(const bhalf8*)tr;
      bhalf8 b1 = *(const bhalf8*)(tr + 32);
      floatx4 a = (floatx4){0.f, 0.f, 0.f, 0.f};
      a = __builtin_amdgcn_mfma_f32_16x16x32_bf16(aq0, b0, a, 0, 0, 0);
      a = __builtin_amdgcn_mfma_f32_16x16x32_bf16(aq1, b1, a, 0, 0, 0);
      fresh[ct] = a;
    }
    // diagonal scatter into wave-private S2c (local rows lr = quad*4+r):
    // fresh (row,t): col=row+63-t when t>=row; carry: col=row-1-t when t<row
#pragma unroll
    for (int ct = 0; ct < 4; ++ct) {
      int t = ct * 16 + ln15;
#pragma unroll
      for (int r = 0; r < 4; ++r) {
        int row = wrow + quad * 4 + r;
        int lr = quad * 4 + r;
        if (t >= row) S2w[lr * 68 + (row + 63 - t)] = fresh[ct][r];
        else          S2w[lr * 68 + (row - 1 - t)] = carry[ct][r];
      }
      carry[ct] = fresh[ct];
    }

    // Gather ALL S2c reads into registers FIRST (S2c dead afterwards ->
    // Ps may overwrite the slab)...
    float s2f[4][4];
#pragma unroll
    for (int ct = 0; ct < 4; ++ct)
#pragma unroll
      for (int r = 0; r < 4; ++r)
        s2f[ct][r] = S2w[(quad * 4 + r) * 68 + ct * 16 + ln15];

    // ...then S1 = Q K'^T + rel band via MFMA C-operand (K' pre-scaled 1/8);
    // p = exp(s) shift-free; Ps write at 3-bit-XOR-swizzled chunk.
#pragma unroll
    for (int ct = 0; ct < 4; ++ct) {
      floatx4 cva = {s2f[ct][0], s2f[ct][1], s2f[ct][2], s2f[ct][3]};
      bhalf8 b0 = *(bhalf8*)&Ksc[(ct * 16 + ln15) * 32 + qsw];
      bhalf8 b1 = *(bhalf8*)&Ksc[2048 + (ct * 16 + ln15) * 32 + qsw];
      floatx4 a = __builtin_amdgcn_mfma_f32_16x16x32_bf16(aq0, b0, cva, 0, 0, 0);
      a = __builtin_amdgcn_mfma_f32_16x16x32_bf16(aq1, b1, a, 0, 0, 0);
#pragma unroll
      for (int r = 0; r < 4; ++r) {
        float p = __expf(a[r]);
        lsum[r] += p;
        int lr = quad * 4 + r;
        int pch = ((ct * 2 + (ln15 >> 3)) ^ ((lr >> 1) & 7)) * 8;
        Psw[lr * 136 + pch + (ln15 & 7)] = __float2bfloat16(p);
      }
    }

    bhalf8 ap0 = *(bhalf8*)&Psw[ln15 * 136 + pc0];
    bhalf8 ap1 = *(bhalf8*)&Psw[ln15 * 136 + pc1];
#pragma unroll
    for (int ct = 0; ct < 4; ++ct) {
      bhalf8 b0 = *(bhalf8*)&Vsc[(ct * 16 + ln15) * 32 + qsw];
      bhalf8 b1 = *(bhalf8*)&Vsc[2048 + (ct * 16 + ln15) * 32 + qsw];
      o[ct] = __builtin_amdgcn_mfma_f32_16x16x32_bf16(ap0, b0, o[ct], 0, 0, 0);
      o[ct] = __builtin_amdgcn_mfma_f32_16x16x32_bf16(ap1, b1, o[ct], 0, 0, 0);
    }
    cur ^= 1;
  }

  // epilogue: one shuffle-reduce of l per row; locally-normalized partial + l
  bf16* Oz = Opart + (size_t)z * SEQ * DM;
#pragma unroll
  for (int r = 0; r < 4; ++r) {
    float l = lsum[r];
    l += __shfl_xor(l, 1); l += __shfl_xor(l, 2);
    l += __shfl_xor(l, 4); l += __shfl_xor(l, 8);
    float inv = 1.f / l;
    int row = i0 + wrow + quad * 4 + r;
#pragma unroll
    for (int ct = 0; ct < 4; ++ct)
      Oz[(size_t)row * DM + h * HDM + ct * 16 + ln15] =
          __float2bfloat16(o[ct][r] * inv);
    if (ln15 == 0)
      lws[((size_t)z * NH + h) * SEQ + row] = l;
  }
}

// ---- merge the two key-halves: O = w0*O0n + w1*O1n, w = l / (l0+l1)
__global__ __launch_bounds__(256) void attn_merge(
    const bf16* __restrict__ O0, const bf16* __restrict__ O1,
    const float* __restrict__ lws, bf16* __restrict__ O)
{
  const int i = blockIdx.x;
  const int tid = threadIdx.x;
  __shared__ float w0s[NH], w1s[NH];
  if (tid < NH) {
    float l0 = lws[((size_t)0 * NH + tid) * SEQ + i];
    float l1 = lws[((size_t)1 * NH + tid) * SEQ + i];
    float inv = 1.f / (l0 + l1);
    w0s[tid] = l0 * inv; w1s[tid] = l1 * inv;
  }
  __syncthreads();
  const int d = tid * 4;
  const float w0 = w0s[d >> 6], w1 = w1s[d >> 6];
  union { bf16 h[4]; float2 f; } a0, a1, ov;
  a0.f = *(const float2*)&O0[(size_t)i * DM + d];
  a1.f = *(const float2*)&O1[(size_t)i * DM + d];
#pragma unroll
  for (int e = 0; e < 4; ++e)
    ov.h[e] = __float2bfloat16(w0 * __bfloat162float(a0.h[e]) +
                               w1 * __bfloat162float(a1.h[e]));
  *(float2*)&O[(size_t)i * DM + d] = ov.f;
}

extern "C" void kernel_launch(void* const* d_in, const int* in_sizes, int n_in,
                              void* d_out, int out_size, void* d_ws, size_t ws_size,
                              hipStream_t stream) {
  const float* x   = (const float*)d_in[0];
  const float* Wq  = (const float*)d_in[1];
  const float* bq  = (const float*)d_in[2];
  const float* Wk  = (const float*)d_in[3];
  const float* bk  = (const float*)d_in[4];
  const float* Wv  = (const float*)d_in[5];
  const float* bv  = (const float*)d_in[6];
  const float* Wo  = (const float*)d_in[7];
  const float* bo  = (const float*)d_in[8];
  const float* rel = (const float*)d_in[9];
  float* out = (float*)d_out;

  const size_t SD = (size_t)SEQ * DM;      // 2M elems
  bf16* qws = (bf16*)d_ws;                 // [H][S][64]
  bf16* kws = qws + SD;                    // [H][S][64] (pre-scaled by 1/8)
  bf16* vws = kws + SD;                    // Vt [D][S]
  bf16* ows = vws + SD;                    // [S][D] merged attn out
  bf16* xbf = ows + SD;                    // [S][D]
  bf16* wt  = xbf + SD;                    // 4 x [n][k] (q,k,v,o)
  bf16* tbf = wt + 4 * (size_t)DM * DM;    // [4096][64]
  bf16* opart = tbf + (size_t)4096 * HDM;  // 2 x [S][D] partials
  float* lws  = (float*)(opart + 2 * SD);  // [2][NH][SEQ]

  prep<<<3328, 256, 0, stream>>>(x, rel, Wq, Wk, Wv, Wo, xbf, tbf, wt);
  gemm_qkv128<<<dim3(8, 16, 3), 256, 0, stream>>>(xbf, wt, bq, bk, bv, qws);
  attn_flash<<<dim3(SEQ / 64, NH, 2), 256, 0, stream>>>(qws, kws, vws, tbf,
                                                        opart, lws);
  attn_merge<<<SEQ, 256, 0, stream>>>(opart, opart + SD, lws, ows);
  gemm_out<<<dim3(16, 32), 256, 0, stream>>>(ows, wt + 3 * (size_t)DM * DM, bo, out);
}

// Round 14
// 193.406 us; speedup vs baseline: 1.2272x; 1.2272x over previous
//
#include <hip/hip_runtime.h>
#include <hip/hip_bf16.h>

#define SEQ 2048
#define DM  1024
#define NH  16
#define HDM 64

typedef __hip_bfloat16 bf16;
typedef __bf16 bhalf8 __attribute__((ext_vector_type(8)));
typedef float floatx4 __attribute__((ext_vector_type(4)));

__device__ __forceinline__ void async_cp16(const void* g, void* l) {
  __builtin_amdgcn_global_load_lds(
      (const __attribute__((address_space(1))) void*)g,
      (__attribute__((address_space(3))) void*)l, 16, 0, 0);
}

// ---- fused prep: x f32->bf16; rel f32->bf16 padded [4096][64]; W transpose
__global__ __launch_bounds__(256) void prep(
    const float* __restrict__ x, const float* __restrict__ T,
    const float* __restrict__ W0, const float* __restrict__ W1,
    const float* __restrict__ W2, const float* __restrict__ W3,
    bf16* __restrict__ xbf, bf16* __restrict__ Tbf, bf16* __restrict__ WtBase)
{
  __shared__ float tile[64][69];
  const int b = blockIdx.x;
  const int tid = threadIdx.x;
  if (b < 2048) {
    int c = b * 256 + tid;
    float4 v = *(const float4*)&x[(size_t)c * 4];
    union { bf16 h[4]; float2 f; } u;
    u.h[0] = __float2bfloat16(v.x); u.h[1] = __float2bfloat16(v.y);
    u.h[2] = __float2bfloat16(v.z); u.h[3] = __float2bfloat16(v.w);
    *(float2*)&xbf[(size_t)c * 4] = u.f;
  } else if (b < 2304) {
    int ct = (b - 2048) * 256 + tid;       // [0, 65536)
    union { bf16 h[4]; float2 f; } u;
#pragma unroll
    for (int e = 0; e < 4; ++e) {
      int se = ct * 4 + e;
      if (se >= 4095 * 64) se -= 64;       // pad row 4095 = dup of 4094
      u.h[e] = __float2bfloat16(T[se]);
    }
    *(float2*)&Tbf[(size_t)ct * 4] = u.f;
  } else {
    int tb = b - 2304;                     // [0, 1024)
    int z = tb >> 8, rem = tb & 255;
    const float* W = (z == 0) ? W0 : (z == 1) ? W1 : (z == 2) ? W2 : W3;
    bf16* Wt = WtBase + (size_t)z * DM * DM;
    const int kb = (rem >> 4) * 64, nb = (rem & 15) * 64;
    const int r = tid >> 4, c4 = (tid & 15) * 4;
#pragma unroll
    for (int rr = 0; rr < 4; ++rr) {
      float4 v = *(const float4*)&W[(size_t)(kb + rr * 16 + r) * DM + nb + c4];
      tile[rr * 16 + r][c4 + 0] = v.x; tile[rr * 16 + r][c4 + 1] = v.y;
      tile[rr * 16 + r][c4 + 2] = v.z; tile[rr * 16 + r][c4 + 3] = v.w;
    }
    __syncthreads();
    const int w = tid >> 6, l = tid & 63;
#pragma unroll
    for (int i = 0; i < 16; ++i) {
      int n = nb + w * 16 + i;
      Wt[(size_t)n * DM + kb + l] = __float2bfloat16(tile[l][w * 16 + i]);
    }
  }
}

// ---- MFMA GEMM core 64x64 (gemm_out): BK=64 as two BK=32 panels.
// Chunk XOR swizzle: linear DMA dest + inverse-swizzled global source +
// swizzled read. Validated rounds 3-9.
__device__ __forceinline__ void gemm64_core(
    const bf16* __restrict__ A, const bf16* __restrict__ Bt,
    bf16* As, bf16* Bs, int bm, int bn, floatx4 (&acc)[4])
{
  const int tid = threadIdx.x;
  const int lane = tid & 63;
  const int w = tid >> 6;
  const int ln15 = lane & 15, quad = lane >> 4;
  const int qs8  = (quad ^ ((ln15 >> 1) & 3)) * 8;        // swizzled read col
  const int srow = tid >> 2;                               // staging phys row
  const int scol = ((tid & 3) ^ ((tid >> 3) & 3)) * 8;     // swizzled src col

  for (int k0 = 0; k0 < DM; k0 += 64) {
    async_cp16(A  + (size_t)(bm + srow) * DM + k0 + scol,      As + tid * 8);
    async_cp16(A  + (size_t)(bm + srow) * DM + k0 + 32 + scol, As + 2048 + tid * 8);
    async_cp16(Bt + (size_t)(bn + srow) * DM + k0 + scol,      Bs + tid * 8);
    async_cp16(Bt + (size_t)(bn + srow) * DM + k0 + 32 + scol, Bs + 2048 + tid * 8);
    __syncthreads();
#pragma unroll
    for (int kk = 0; kk < 2; ++kk) {
      bhalf8 af = *(bhalf8*)&As[kk * 2048 + (w * 16 + ln15) * 32 + qs8];
      bhalf8 bfr[4];
#pragma unroll
      for (int j = 0; j < 4; ++j)
        bfr[j] = *(bhalf8*)&Bs[kk * 2048 + (j * 16 + ln15) * 32 + qs8];
#pragma unroll
      for (int j = 0; j < 4; ++j)
        acc[j] = __builtin_amdgcn_mfma_f32_16x16x32_bf16(af, bfr[j], acc[j], 0, 0, 0);
    }
    __syncthreads();
  }
}

// ---- QKV projection, 128x128 tile, BK=64, 4 waves in 2x2, chunk-XOR swizzle.
// z==1 (K) output scaled by 1/8 (bf16-exact).
__global__ __launch_bounds__(256) void gemm_qkv128(
    const bf16* __restrict__ A, const bf16* __restrict__ Wt3,
    const float* __restrict__ bq, const float* __restrict__ bk,
    const float* __restrict__ bv, bf16* __restrict__ outbase)
{
  __shared__ __align__(16) bf16 As[128 * 64];
  __shared__ __align__(16) bf16 Bs[128 * 64];
  const int z = blockIdx.z;
  const bf16* Bt = Wt3 + (size_t)z * DM * DM;
  const float* bias = (z == 0) ? bq : (z == 1) ? bk : bv;
  const float kscale = (z == 1) ? 0.125f : 1.0f;
  bf16* C = outbase + (size_t)z * SEQ * DM;
  const int bm = blockIdx.y * 128, bn = blockIdx.x * 128;
  const int tid = threadIdx.x;
  const int lane = tid & 63, w = tid >> 6;
  const int ln15 = lane & 15, quad = lane >> 4;
  const int wr = (w >> 1) * 64, wc = (w & 1) * 64;

  floatx4 acc[4][4];
#pragma unroll
  for (int mi = 0; mi < 4; ++mi)
#pragma unroll
    for (int nj = 0; nj < 4; ++nj) acc[mi][nj] = (floatx4){0.f, 0.f, 0.f, 0.f};

  for (int k0 = 0; k0 < DM; k0 += 64) {
#pragma unroll
    for (int t = 0; t < 4; ++t) {
      int cid = t * 256 + tid;
      int row = cid >> 3;
      int scol = ((cid & 7) ^ (row & 7)) * 8;   // inverse-swizzled source col
      async_cp16(A  + (size_t)(bm + row) * DM + k0 + scol, As + cid * 8);
      async_cp16(Bt + (size_t)(bn + row) * DM + k0 + scol, Bs + cid * 8);
    }
    __syncthreads();
#pragma unroll
    for (int kk = 0; kk < 2; ++kk) {
      const int chs = ((kk * 4 + quad) ^ (ln15 & 7)) * 8;  // swizzled read col
      bhalf8 af[4], bfr[4];
#pragma unroll
      for (int mi = 0; mi < 4; ++mi)
        af[mi] = *(bhalf8*)&As[(wr + mi * 16 + ln15) * 64 + chs];
#pragma unroll
      for (int nj = 0; nj < 4; ++nj)
        bfr[nj] = *(bhalf8*)&Bs[(wc + nj * 16 + ln15) * 64 + chs];
#pragma unroll
      for (int mi = 0; mi < 4; ++mi)
#pragma unroll
        for (int nj = 0; nj < 4; ++nj)
          acc[mi][nj] = __builtin_amdgcn_mfma_f32_16x16x32_bf16(
              af[mi], bfr[nj], acc[mi][nj], 0, 0, 0);
    }
    __syncthreads();
  }

#pragma unroll
  for (int nj = 0; nj < 4; ++nj) {
    int col = bn + wc + nj * 16 + ln15;
    float bv_ = bias[col];
#pragma unroll
    for (int mi = 0; mi < 4; ++mi) {
#pragma unroll
      for (int r = 0; r < 4; ++r) {
        int row = bm + wr + mi * 16 + quad * 4 + r;
        float v = (acc[mi][nj][r] + bv_) * kscale;
        if (z < 2)
          C[((size_t)(col >> 6) * SEQ + row) * HDM + (col & 63)] = __float2bfloat16(v);
        else
          C[(size_t)col * SEQ + row] = __float2bfloat16(v);
      }
    }
  }
}

// ---- output projection: f32 out row-major
__global__ __launch_bounds__(256) void gemm_out(
    const bf16* __restrict__ A, const bf16* __restrict__ Bt,
    const float* __restrict__ bias, float* __restrict__ C)
{
  __shared__ __align__(16) bf16 As[64 * 64];
  __shared__ __align__(16) bf16 Bs[64 * 64];
  const int bm = blockIdx.y * 64, bn = blockIdx.x * 64;
  floatx4 acc[4];
#pragma unroll
  for (int j = 0; j < 4; ++j) acc[j] = (floatx4){0.f, 0.f, 0.f, 0.f};
  gemm64_core(A, Bt, As, Bs, bm, bn, acc);

  const int lane = threadIdx.x & 63;
  const int w = threadIdx.x >> 6;
  const int ln15 = lane & 15, quad = lane >> 4;
#pragma unroll
  for (int j = 0; j < 4; ++j) {
    int col = bn + j * 16 + ln15;
    float bv_ = bias[col];
#pragma unroll
    for (int r = 0; r < 4; ++r) {
      int row = bm + w * 16 + quad * 4 + r;
      C[(size_t)row * DM + col] = acc[j][r] + bv_;
    }
  }
}

// ---- Flash attention, SINGLE-PASS over all 32 K/V tiles (key-split
// COLLAPSED). Core is the round-9-proven version byte-for-byte (staged
// K/V/T DMA, double-buffer, one barrier/iter, chunk-XOR swizzles, Ps
// [64][64] 3-bit XOR, shift-free softmax). r11 lesson: per-iter direct-
// global T demand-loads are latency-death -- T stays LDS-staged. Each
// block now owns a full Q-row-block: l and o accumulate over all tiles,
// epilogue writes the FINAL normalized output -- (o0+o1)/(l0+l1) is
// exactly what the old merge computed, minus one bf16 rounding. Saves
// the attn_merge launch + 16 MB opart/lws round-trip; grid 512 = exactly
// 2 blocks/CU resident (one generation, no tail).
__global__ __launch_bounds__(256, 2) void attn_flash(
    const bf16* __restrict__ Q, const bf16* __restrict__ K,
    const bf16* __restrict__ Vt, const bf16* __restrict__ Tb,
    bf16* __restrict__ O)
{
  const int i0   = blockIdx.x * 64;
  const int h    = blockIdx.y;
  const int tid  = threadIdx.x;
  const int lane = tid & 63;
  const int wrow = (tid >> 6) * 16;
  const int ln15 = lane & 15;
  const int quad = lane >> 4;

  // [0,16384) K bufs | [16384,32768) V bufs | [32768,49152) T bufs
  // [49152,57344) Ps [64][64] swz | [58368,75264) S2c f32 [64][66]
  // (Qs overlaps S2c, pre-loop only; loop-top barrier separates)
  __shared__ __align__(16) unsigned char smem[75264];
  bf16*  Ps  = (bf16*)(smem + 49152);       // [64][64], chunk-XOR swizzled
  float* S2c = (float*)(smem + 58368);      // [64][66] f32
  bf16*  Qs  = (bf16*)(smem + 58368);       // [64][72]

  const bf16* Qg = Q  + ((size_t)h * SEQ + i0) * HDM;
  const bf16* Kg = K  + (size_t)h * SEQ * HDM;
  const bf16* Vg = Vt + (size_t)h * HDM * SEQ;

  // staging: dest linear (tid*8), global source chunk pre-swizzled so that
  // phys[row][c] = logical[row][c ^ ((row>>1)&3)]
  const int r4 = tid >> 2;
  const int c8s = (((tid & 3) ^ ((r4 >> 1) & 3)) * 8);
  auto stage = [&](int jt_, int b) {
    int j0_ = jt_ * 64;
    int rb_ = i0 - j0_ + SEQ - HDM;
    bf16* Kd = (bf16*)smem + b * 4096;
    bf16* Vd = (bf16*)smem + 8192 + b * 4096;
    bf16* Td = (bf16*)smem + 16384 + b * 4096;
    async_cp16(Kg + (size_t)(j0_ + r4) * HDM + c8s,        Kd + tid * 8);
    async_cp16(Kg + (size_t)(j0_ + r4) * HDM + 32 + c8s,   Kd + 2048 + tid * 8);
    async_cp16(Vg + (size_t)r4 * SEQ + j0_ + c8s,          Vd + tid * 8);
    async_cp16(Vg + (size_t)r4 * SEQ + j0_ + 32 + c8s,     Vd + 2048 + tid * 8);
    async_cp16(Tb + (size_t)(rb_ + r4) * HDM + c8s,        Td + tid * 8);
    async_cp16(Tb + (size_t)(rb_ + r4) * HDM + 32 + c8s,   Td + 2048 + tid * 8);
  };

  stage(0, 0);   // prefetch first tile; lands during Q/carry preamble

#pragma unroll
  for (int t = 0; t < 2; ++t) {
    int id = tid + t * 256;
    int r = id >> 3, c = (id & 7) * 8;
    *(float4*)&Qs[r * 72 + c] = *(const float4*)&Qg[(size_t)r * HDM + c];
  }
  __syncthreads();

  const bhalf8 aq0 = *(bhalf8*)&Qs[(wrow + ln15) * 72 + quad * 8];
  const bhalf8 aq1 = *(bhalf8*)&Qs[(wrow + ln15) * 72 + quad * 8 + 32];

  floatx4 o[4];
  float lsum[4];
#pragma unroll
  for (int c = 0; c < 4; ++c) { o[c] = (floatx4){0.f, 0.f, 0.f, 0.f}; lsum[c] = 0.f; }

  const int rb0 = i0 + SEQ - HDM;
  // carry init: virtual previous iter's fresh band (rows rb0+64+[0,64)),
  // one-time direct-global B-frags (rows <= 4095, in padded Tb).
  floatx4 carry[4];
#pragma unroll
  for (int ct = 0; ct < 4; ++ct) {
    const bf16* tr = Tb + (size_t)(rb0 + 64 + ct * 16 + ln15) * HDM + quad * 8;
    bhalf8 b0 = *(const bhalf8*)tr;
    bhalf8 b1 = *(const bhalf8*)(tr + 32);
    floatx4 a = (floatx4){0.f, 0.f, 0.f, 0.f};
    a = __builtin_amdgcn_mfma_f32_16x16x32_bf16(aq0, b0, a, 0, 0, 0);
    a = __builtin_amdgcn_mfma_f32_16x16x32_bf16(aq1, b1, a, 0, 0, 0);
    carry[ct] = a;
  }

  // swizzled frag-read column for K/V/T tiles (phys = quad ^ ((row>>1)&3))
  const int qsw = (quad ^ ((ln15 >> 1) & 3)) * 8;
  // Ps read columns: row = wrow+ln15 -> xor = ln15>>1 (3-bit)
  const int pc0 = (quad ^ (ln15 >> 1)) * 8;
  const int pc1 = pc0 ^ 32;
  const int prow = wrow + ln15;

  int cur = 0;
  for (int jt = 0; jt < 32; ++jt) {
    __syncthreads();   // drains vmcnt: buf[cur] DMA complete; prev readers done
    if (jt + 1 < 32) stage(jt + 1, cur ^ 1);   // overlap with compute
    const bf16* Ksc = (bf16*)smem + cur * 4096;
    const bf16* Vsc = (bf16*)smem + 8192 + cur * 4096;
    const bf16* Tsc = (bf16*)smem + 16384 + cur * 4096;

    // fresh band: rows rbase+[0,64)
    floatx4 fresh[4];
#pragma unroll
    for (int ct = 0; ct < 4; ++ct) {
      bhalf8 b0 = *(bhalf8*)&Tsc[(ct * 16 + ln15) * 32 + qsw];
      bhalf8 b1 = *(bhalf8*)&Tsc[2048 + (ct * 16 + ln15) * 32 + qsw];
      floatx4 a = (floatx4){0.f, 0.f, 0.f, 0.f};
      a = __builtin_amdgcn_mfma_f32_16x16x32_bf16(aq0, b0, a, 0, 0, 0);
      a = __builtin_amdgcn_mfma_f32_16x16x32_bf16(aq1, b1, a, 0, 0, 0);
      fresh[ct] = a;
    }
    // diagonal scatter, row-major (wave-private rows):
    // fresh (row,t): col=row+63-t when t>=row; carry: col=row-1-t when t<row
#pragma unroll
    for (int ct = 0; ct < 4; ++ct) {
      int t = ct * 16 + ln15;
#pragma unroll
      for (int r = 0; r < 4; ++r) {
        int row = wrow + quad * 4 + r;
        if (t >= row) S2c[row * 66 + (row + 63 - t)] = fresh[ct][r];
        else          S2c[row * 66 + (row - 1 - t)] = carry[ct][r];
      }
      carry[ct] = fresh[ct];
    }

    // S1 = Q K'^T + rel band via MFMA C-operand (K' pre-scaled by 1/8);
    // p = exp(s) shift-free; Ps write at 3-bit-XOR-swizzled chunk.
#pragma unroll
    for (int ct = 0; ct < 4; ++ct) {
      floatx4 s2f;
#pragma unroll
      for (int r = 0; r < 4; ++r)
        s2f[r] = S2c[(wrow + quad * 4 + r) * 66 + ct * 16 + ln15];
      bhalf8 b0 = *(bhalf8*)&Ksc[(ct * 16 + ln15) * 32 + qsw];
      bhalf8 b1 = *(bhalf8*)&Ksc[2048 + (ct * 16 + ln15) * 32 + qsw];
      floatx4 a = __builtin_amdgcn_mfma_f32_16x16x32_bf16(aq0, b0, s2f, 0, 0, 0);
      a = __builtin_amdgcn_mfma_f32_16x16x32_bf16(aq1, b1, a, 0, 0, 0);
#pragma unroll
      for (int r = 0; r < 4; ++r) {
        float p = __expf(a[r]);
        lsum[r] += p;
        int row = wrow + quad * 4 + r;
        int pch = ((ct * 2 + (ln15 >> 3)) ^ ((row >> 1) & 7)) * 8;
        Ps[row * 64 + pch + (ln15 & 7)] = __float2bfloat16(p);
      }
    }

    bhalf8 ap0 = *(bhalf8*)&Ps[prow * 64 + pc0];
    bhalf8 ap1 = *(bhalf8*)&Ps[prow * 64 + pc1];
#pragma unroll
    for (int ct = 0; ct < 4; ++ct) {
      bhalf8 b0 = *(bhalf8*)&Vsc[(ct * 16 + ln15) * 32 + qsw];
      bhalf8 b1 = *(bhalf8*)&Vsc[2048 + (ct * 16 + ln15) * 32 + qsw];
      o[ct] = __builtin_amdgcn_mfma_f32_16x16x32_bf16(ap0, b0, o[ct], 0, 0, 0);
      o[ct] = __builtin_amdgcn_mfma_f32_16x16x32_bf16(ap1, b1, o[ct], 0, 0, 0);
    }
    cur ^= 1;
  }

  // epilogue: one shuffle-reduce of l per row; FINAL normalized output
#pragma unroll
  for (int r = 0; r < 4; ++r) {
    float l = lsum[r];
    l += __shfl_xor(l, 1); l += __shfl_xor(l, 2);
    l += __shfl_xor(l, 4); l += __shfl_xor(l, 8);
    float inv = 1.f / l;
    int row = i0 + wrow + quad * 4 + r;
#pragma unroll
    for (int ct = 0; ct < 4; ++ct)
      O[(size_t)row * DM + h * HDM + ct * 16 + ln15] =
          __float2bfloat16(o[ct][r] * inv);
  }
}

extern "C" void kernel_launch(void* const* d_in, const int* in_sizes, int n_in,
                              void* d_out, int out_size, void* d_ws, size_t ws_size,
                              hipStream_t stream) {
  const float* x   = (const float*)d_in[0];
  const float* Wq  = (const float*)d_in[1];
  const float* bq  = (const float*)d_in[2];
  const float* Wk  = (const float*)d_in[3];
  const float* bk  = (const float*)d_in[4];
  const float* Wv  = (const float*)d_in[5];
  const float* bv  = (const float*)d_in[6];
  const float* Wo  = (const float*)d_in[7];
  const float* bo  = (const float*)d_in[8];
  const float* rel = (const float*)d_in[9];
  float* out = (float*)d_out;

  const size_t SD = (size_t)SEQ * DM;      // 2M elems
  bf16* qws = (bf16*)d_ws;                 // [H][S][64]
  bf16* kws = qws + SD;                    // [H][S][64] (pre-scaled by 1/8)
  bf16* vws = kws + SD;                    // Vt [D][S]
  bf16* ows = vws + SD;                    // [S][D] attn out (final, normalized)
  bf16* xbf = ows + SD;                    // [S][D]
  bf16* wt  = xbf + SD;                    // 4 x [n][k] (q,k,v,o)
  bf16* tbf = wt + 4 * (size_t)DM * DM;    // [4096][64]

  prep<<<3328, 256, 0, stream>>>(x, rel, Wq, Wk, Wv, Wo, xbf, tbf, wt);
  gemm_qkv128<<<dim3(8, 16, 3), 256, 0, stream>>>(xbf, wt, bq, bk, bv, qws);
  attn_flash<<<dim3(SEQ / 64, NH), 256, 0, stream>>>(qws, kws, vws, tbf, ows);
  gemm_out<<<dim3(16, 32), 256, 0, stream>>>(ows, wt + 3 * (size_t)DM * DM, bo, out);
}